// Round 7
// baseline (857.766 us; speedup 1.0000x reference)
//
#include <hip/hip_runtime.h>

#define B_   64
#define T_   1024
#define D_   128
#define SCALE_ 0.08838834764831845f
#define FILL_  (-4294967295.0f)

typedef __attribute__((ext_vector_type(8))) short short8v;
typedef __attribute__((ext_vector_type(4))) float f32x4;

#define MFMA16(A,Bv,C) __builtin_amdgcn_mfma_f32_16x16x32_bf16((A),(Bv),(C),0,0,0)

// truncation-split: f ~= hi + lo with hi,lo bf16 (error ~2^-17 rel)
__device__ __forceinline__ void split8(const float f[8], short8v& h, short8v& l) {
#pragma unroll
    for (int i = 0; i < 8; ++i) {
        const unsigned int u = __float_as_uint(f[i]);
        h[i] = (short)(u >> 16);
        const float r = f[i] - __uint_as_float(u & 0xffff0000u);
        l[i] = (short)(__float_as_uint(r) >> 16);
    }
}

// One block per (batch, 32-row q-tile); 512 threads = 8 waves.
// QK^T (validated r3/r5/r6): wave w owns k-cols [w*128, w*128+128); hi/lo split x3.
// attn store: per-wave LDS transpose (TBUF[w][8][132]) -> 512B-contiguous float4
//   row stores (full cache lines; fixes r5/r6 write amplification). No barriers.
// PV: P read back from attn in GLOBAL (L2-hot, written by this block; one
//   __syncthreads drains stores) -> no Pc LDS, no PV barriers; 32 independent
//   k-chunks give ILP to hide strided V-load latency. Wave w owns d-cols 16.
// result: LDS transpose (RBUF aliases TBUF) -> contiguous float4 stores.
// Occupancy is register-bound (~16 waves/CU: 64 VGPR + 64 AGPR acc), known.
__global__ __launch_bounds__(512, 4)
void mha_kernel(const float* __restrict__ Kp, const float* __restrict__ Vp,
                const float* __restrict__ Qp, const unsigned char* __restrict__ Mp,
                const float* __restrict__ QMp, float* __restrict__ Orp,
                float* __restrict__ Oap)
{
    __shared__ __align__(16) float TBUF[8][8][132];   // 33792 B; also aliased as RBUF[32][132]
    __shared__ float redA[8 * 32];
    __shared__ float redB[8 * 32];

    const int tid  = threadIdx.x;
    const int w    = tid >> 6;
    const int lane = tid & 63;
    const int g    = lane >> 4;
    const int c    = lane & 15;
    // XCD-aware bijective swizzle: grid=2048=8*256, chunked per XCD
    const int wg   = (blockIdx.x & 7) * 256 + (blockIdx.x >> 3);
    const int b    = wg >> 5;
    const int q0   = (wg & 31) << 5;

    // ---- mask dtype auto-detect (u8 bool vs i32) ----
    const unsigned int* mw = (const unsigned int*)Mp;
    unsigned int bad = 0u;
#pragma unroll
    for (int i = 0; i < 16; ++i) bad |= (unsigned int)(mw[i] > 1u);
    const bool m32 = (bad == 0u);

    const size_t bt = (size_t)b * T_;

    // =================== QK^T ===================
    f32x4 acc[2][8];
#pragma unroll
    for (int mt = 0; mt < 2; ++mt)
#pragma unroll
        for (int nt = 0; nt < 8; ++nt) acc[mt][nt] = (f32x4)0.f;

#pragma unroll
    for (int ks = 0; ks < 4; ++ks) {
        short8v qh[2], ql[2];
#pragma unroll
        for (int mt = 0; mt < 2; ++mt) {
            const float* qp = Qp + (bt + q0 + mt*16 + c) * D_ + ks*32 + g*8;
            float f[8];
#pragma unroll
            for (int i = 0; i < 8; ++i) f[i] = qp[i];
            split8(f, qh[mt], ql[mt]);
        }
#pragma unroll
        for (int nt = 0; nt < 8; ++nt) {
            const float* kp = Kp + (bt + w*128 + nt*16 + c) * D_ + ks*32 + g*8;
            float f[8];
#pragma unroll
            for (int i = 0; i < 8; ++i) f[i] = kp[i];
            short8v kh, kl;
            split8(f, kh, kl);
#pragma unroll
            for (int mt = 0; mt < 2; ++mt) {
                acc[mt][nt] = MFMA16(qh[mt], kh, acc[mt][nt]);
                acc[mt][nt] = MFMA16(qh[mt], kl, acc[mt][nt]);
                acc[mt][nt] = MFMA16(ql[mt], kh, acc[mt][nt]);
            }
        }
    }

    // =================== mask + scale + softmax ===================
    float rmax[2][4];
#pragma unroll
    for (int mt = 0; mt < 2; ++mt)
#pragma unroll
    for (int rg = 0; rg < 4; ++rg) {
        const int row = mt*16 + g*4 + rg;
        const size_t mrow = (bt + q0 + row) * (size_t)T_ + w*128;
        float rm = -3.0e38f;
        if (m32) {
            const int* mi = (const int*)Mp;
#pragma unroll
            for (int nt = 0; nt < 8; ++nt) {
                float s = acc[mt][nt][rg] * SCALE_;
                if (mi[mrow + nt*16 + c]) s = FILL_;
                acc[mt][nt][rg] = s;
                rm = fmaxf(rm, s);
            }
        } else {
#pragma unroll
            for (int nt = 0; nt < 8; ++nt) {
                float s = acc[mt][nt][rg] * SCALE_;
                if (Mp[mrow + nt*16 + c]) s = FILL_;
                acc[mt][nt][rg] = s;
                rm = fmaxf(rm, s);
            }
        }
        rmax[mt][rg] = rm;
    }
#pragma unroll
    for (int mt = 0; mt < 2; ++mt)
#pragma unroll
    for (int rg = 0; rg < 4; ++rg)
#pragma unroll
        for (int off = 1; off < 16; off <<= 1)
            rmax[mt][rg] = fmaxf(rmax[mt][rg], __shfl_xor(rmax[mt][rg], off, 64));
    if (c == 0) {
#pragma unroll
        for (int mt = 0; mt < 2; ++mt)
#pragma unroll
        for (int rg = 0; rg < 4; ++rg)
            redA[w*32 + mt*16 + g*4 + rg] = rmax[mt][rg];
    }
    __syncthreads();
    float rsum[2][4];
#pragma unroll
    for (int mt = 0; mt < 2; ++mt)
#pragma unroll
    for (int rg = 0; rg < 4; ++rg) {
        const int row = mt*16 + g*4 + rg;
        float m = redA[row];
#pragma unroll
        for (int w2 = 1; w2 < 8; ++w2) m = fmaxf(m, redA[w2*32 + row]);
        float s = 0.f;
#pragma unroll
        for (int nt = 0; nt < 8; ++nt) {
            const float e = __expf(acc[mt][nt][rg] - m);
            acc[mt][nt][rg] = e;
            s += e;
        }
#pragma unroll
        for (int off = 1; off < 16; off <<= 1) s += __shfl_xor(s, off, 64);
        rsum[mt][rg] = s;
    }
    if (c == 0) {
#pragma unroll
        for (int mt = 0; mt < 2; ++mt)
#pragma unroll
        for (int rg = 0; rg < 4; ++rg)
            redB[w*32 + mt*16 + g*4 + rg] = rsum[mt][rg];
    }
    __syncthreads();

    // finalize p = e * query_mask / sum (held in acc)
#pragma unroll
    for (int mt = 0; mt < 2; ++mt)
#pragma unroll
    for (int rg = 0; rg < 4; ++rg) {
        const int row = mt*16 + g*4 + rg;
        float ssum = redB[row];
#pragma unroll
        for (int w2 = 1; w2 < 8; ++w2) ssum += redB[w2*32 + row];
        const float inv = QMp[bt + q0 + row] / ssum;
#pragma unroll
        for (int nt = 0; nt < 8; ++nt) acc[mt][nt][rg] *= inv;
    }

    // ========== attn store: per-wave transpose, full-line coalesced ==========
    // Wave w owns rows 0..31 x k [w*128, w*128+128). 4 rounds of 8 rows.
#pragma unroll
    for (int r8 = 0; r8 < 4; ++r8) {
        const int mt = r8 >> 1;
        if ((g >> 1) == (r8 & 1)) {
            // active lanes hold rows r8*8 + (g&1)*4 + rg; row-local = (g&1)*4+rg
#pragma unroll
            for (int nt = 0; nt < 8; ++nt)
#pragma unroll
            for (int rg = 0; rg < 4; ++rg)
                TBUF[w][(g & 1) * 4 + rg][nt*16 + c] =
                    (mt == 0) ? acc[0][nt][rg] : acc[1][nt][rg];
        }
        __asm__ __volatile__("s_waitcnt lgkmcnt(0)" ::: "memory");
        __builtin_amdgcn_sched_barrier(0);
#pragma unroll
        for (int s = 0; s < 4; ++s) {
            const int rl = 2*s + (lane >> 5);
            const int q4 = (lane & 31) << 2;
            float4 v;
            v.x = TBUF[w][rl][q4 + 0];
            v.y = TBUF[w][rl][q4 + 1];
            v.z = TBUF[w][rl][q4 + 2];
            v.w = TBUF[w][rl][q4 + 3];
            *(float4*)&Oap[(bt + q0 + r8*8 + rl) * (size_t)T_ + w*128 + q4] = v;
        }
        __asm__ __volatile__("s_waitcnt lgkmcnt(0)" ::: "memory");
        __builtin_amdgcn_sched_barrier(0);
    }

    // all attn visible in L2 (syncthreads drains vmcnt) before readback
    __syncthreads();

    // =================== PV: P from attn (L2), V direct; no barriers ===================
    f32x4 o[2];
    o[0] = (f32x4)0.f;
    o[1] = (f32x4)0.f;

    for (int ch = 0; ch < 32; ++ch) {
        short8v ph[2], pl[2];
#pragma unroll
        for (int mt = 0; mt < 2; ++mt) {
            const float* pp = Oap + (bt + q0 + mt*16 + c) * (size_t)T_ + ch*32 + g*8;
            float f[8];
#pragma unroll
            for (int i = 0; i < 8; ++i) f[i] = pp[i];
            split8(f, ph[mt], pl[mt]);
        }
        float fv[8];
        {
            const float* vp = Vp + (bt + ch*32 + g*8) * D_ + w*16 + c;
#pragma unroll
            for (int i = 0; i < 8; ++i) fv[i] = vp[(size_t)i * D_];
        }
        short8v vh, vl;
        split8(fv, vh, vl);
#pragma unroll
        for (int mt = 0; mt < 2; ++mt) {
            o[mt] = MFMA16(ph[mt], vh, o[mt]);
            o[mt] = MFMA16(ph[mt], vl, o[mt]);
            o[mt] = MFMA16(pl[mt], vh, o[mt]);
        }
    }

    // =================== result: LDS transpose -> coalesced stores ===================
    float (*RB)[132] = (float (*)[132])&TBUF[0][0][0];   // [32][132], aliases TBUF
#pragma unroll
    for (int mt = 0; mt < 2; ++mt)
#pragma unroll
    for (int rg = 0; rg < 4; ++rg)
        RB[mt*16 + g*4 + rg][w*16 + c] = o[mt][rg];
    __syncthreads();
#pragma unroll
    for (int it = 0; it < 2; ++it) {
        const int idx = it*512 + tid;
        const int row = idx >> 5;
        const int q4  = (idx & 31) << 2;
        float4 v;
        v.x = RB[row][q4 + 0];
        v.y = RB[row][q4 + 1];
        v.z = RB[row][q4 + 2];
        v.w = RB[row][q4 + 3];
        *(float4*)&Orp[(bt + q0 + row) * D_ + q4] = v;
    }
}

extern "C" void kernel_launch(void* const* d_in, const int* in_sizes, int n_in,
                              void* d_out, int out_size, void* d_ws, size_t ws_size,
                              hipStream_t stream)
{
    const float* Kp  = (const float*)d_in[0];                 // key   [B,T,D]
    const float* Vp  = (const float*)d_in[1];                 // value [B,T,D]
    const float* Qp  = (const float*)d_in[2];                 // query [B,T,D]
    const unsigned char* Mp = (const unsigned char*)d_in[3];  // mask  [B,T,T] (i32, auto-detected)
    const float* QMp = (const float*)d_in[4];                 // query_mask [B,T,1]
    float* Orp = (float*)d_out;                               // result [B,T,D] first
    float* Oap = Orp + (size_t)B_ * T_ * D_;                  // then attn [B,T,T]

    hipLaunchKernelGGL(mha_kernel, dim3(B_ * 32), dim3(512), 0, stream,
                       Kp, Vp, Qp, Mp, QMp, Orp, Oap);
}